// Round 1
// 389.732 us; speedup vs baseline: 1.0232x; 1.0232x over previous
//
#include <hip/hip_runtime.h>
#include <stdint.h>

typedef int v4i __attribute__((ext_vector_type(4)));

static constexpr int MDIM = 8192;   // B * S
static constexpr int NDIM = 4096;   // D_OUT
static constexpr int KDIM = 4096;   // D_IN

static constexpr int QBLOCKS = (MDIM * KDIM / 16) / 256;  // 8192
static constexpr int WBLOCKS = (NDIM * KDIM / 16) / 256;  // 4096

// Async global->LDS, 16B per lane: HW writes lane i at (wave-uniform base) + i*16.
__device__ __forceinline__ void lds_load16(const void* gptr, void* lptr) {
    __builtin_amdgcn_global_load_lds(
        (const __attribute__((address_space(1))) void*)(uintptr_t)gptr,
        (__attribute__((address_space(3))) void*)(uint32_t)(uintptr_t)lptr,
        16, 0, 0);
}

__device__ __forceinline__ int q1(float f, float s) {
    return (int)fminf(fmaxf(__builtin_rintf(f / s), -128.0f), 127.0f);
}
__device__ __forceinline__ int pack4(int a, int b, int c, int d) {
    return (a & 0xff) | ((b & 0xff) << 8) | ((c & 0xff) << 16) | ((d & 0xff) << 24);
}

__global__ __launch_bounds__(256) void prep_k(const float4* __restrict__ x,
                                              int4* __restrict__ xq,
                                              const int4* __restrict__ w,
                                              int4* __restrict__ wq,
                                              const float* __restrict__ s_in) {
    const int b = blockIdx.x;
    if (b < QBLOCKS) {
        const int i = b * 256 + threadIdx.x;
        const float s = s_in[0];
        const float4 v0 = x[4 * i + 0];
        const float4 v1 = x[4 * i + 1];
        const float4 v2 = x[4 * i + 2];
        const float4 v3 = x[4 * i + 3];
        int4 o;
        o.x = pack4(q1(v0.x, s), q1(v0.y, s), q1(v0.z, s), q1(v0.w, s));
        o.y = pack4(q1(v1.x, s), q1(v1.y, s), q1(v1.z, s), q1(v1.w, s));
        o.z = pack4(q1(v2.x, s), q1(v2.y, s), q1(v2.z, s), q1(v2.w, s));
        o.w = pack4(q1(v3.x, s), q1(v3.y, s), q1(v3.z, s), q1(v3.w, s));
        xq[i] = o;
    } else {
        const int i = (b - QBLOCKS) * 256 + threadIdx.x;
        const int4 a = w[4 * i + 0];
        const int4 c = w[4 * i + 1];
        const int4 d = w[4 * i + 2];
        const int4 e = w[4 * i + 3];
        int4 o;
        o.x = pack4(a.x, a.y, a.z, a.w);
        o.y = pack4(c.x, c.y, c.z, c.w);
        o.z = pack4(d.x, d.y, d.z, d.w);
        o.w = pack4(e.x, e.y, e.z, e.w);
        wq[i] = o;
    }
}

// ============================================================================
// 256x256-tile, 8-phase, counted-vmcnt int8 GEMM (port of the bf16 8-phase
// template; i8 16x16x64 is byte-identical in fragment geometry to bf16
// 16x16x32).
//
// Geometry: BK=128 B per K-tile, 2 K-halves (ks) of 64 B. 8 waves = 2M x 4N,
// per-wave output 128x64. LDS 128 KiB: [A|B] x [slot0|slot1] x [ks0|ks1] x
// 256 rows x 64 B.  Row swizzle: 16-B chunk c of row r stored at slot
// c ^ ((r>>1)&3) -> every consecutive-8-lane ds_read_b128 group covers 8
// distinct bank-quads (conflict-free); realized by pre-swizzling the GLOBAL
// source per lane (LDS dest of global_load_lds stays linear).
//
// Schedule (iteration i processes tiles 2i [slot0, phases 0-3] and 2i+1
// [slot1, phases 4-7]; phase p reads only K-half ks(p)):
//   P0: stage s1.A.k1 (tile 2i+1)   P4: stage s0.A.k1 (tile 2i+2)
//   P1: stage s1.B.k1 (tile 2i+1)   P5: stage s0.B.k1 (tile 2i+2)
//   P2: stage s0.A.k0 (tile 2i+2)   P6: stage s1.A.k0 (tile 2i+3)
//   P3: stage s0.B.k0 (tile 2i+2)   P7: stage s1.B.k0 (tile 2i+3)
// vmcnt(4) at end of P3 (completes prev P6/P7 + this P0/P1) and end of P7
// (completes P2..P5) -- never 0 in the main loop. Each stage targets a
// region whose last reader finished >=1 barrier earlier. Last iteration is
// peeled: only P0/P1 stage, vmcnt(0) at its P3.
// ============================================================================
__global__ __launch_bounds__(512, 2) void gemm_i8_k(const int8_t* __restrict__ A,
                                                    const int8_t* __restrict__ Bt,
                                                    float* __restrict__ C,
                                                    const float* __restrict__ w_scale,
                                                    const float* __restrict__ in_scale) {
    __shared__ int8_t lds[131072];

    const int tid  = threadIdx.x;
    const int lane = tid & 63;
    const int wave = tid >> 6;
    const int wr = wave >> 2;          // 0..1  (M half)
    const int wc = wave & 3;           // 0..3  (N quarter)
    const int lm = lane & 15;
    const int q  = lane >> 4;          // 16-B chunk within 64-B K-half

    // XCD-aware swizzle: 512 wgs, 8 XCDs, each XCD gets an 8x8 tile chunk.
    const int bid = blockIdx.x;
    const int xcd = bid & 7;
    const int j   = bid >> 3;
    const int bm  = (xcd >> 1) * 8 + (j >> 3);   // 0..31
    const int bn  = (xcd & 1) * 8 + (j & 7);     // 0..15

    // Staging: round jr (0/1) covers rows jr*128 + (tid>>2); lane chunk slot
    // (tid&3) receives global chunk (tid&3) ^ ((row>>1)&3) = (tid&3)^((tid>>3)&3).
    const int srow  = tid >> 2;
    const int sperm = ((tid & 3) ^ ((tid >> 3) & 3)) << 4;
    const int8_t* gA = A  + (size_t)(bm * 256 + srow) * KDIM + sperm;
    const int8_t* gB = Bt + (size_t)(bn * 256 + srow) * KDIM + sperm;
    const int ldsT = tid * 16;

#define STAGE(MATBASE, GSRC, slot, ks, kbyte)                                              \
    lds_load16(GSRC + (kbyte) + (ks) * 64,                                                 \
               lds + (MATBASE) + (slot) * 32768 + (ks) * 16384 + ldsT);                    \
    lds_load16(GSRC + (kbyte) + (ks) * 64 + 524288,                                        \
               lds + (MATBASE) + (slot) * 32768 + (ks) * 16384 + 8192 + ldsT);

    // Fragment bases. row = wr*128 + mh*64 + mt*16 + lm; (row>>1)&3 == (lm>>1)&3.
    const int fsw = ((q ^ ((lm >> 1) & 3)) << 4);
    const int aB = (wr * 128 + lm) * 64 + fsw;           // + slot*32768 + ks*16384 + mh*4096 + mt*1024
    const int bB = 65536 + (wc * 64 + lm) * 64 + fsw;    // + slot*32768 + ks*16384 + nt*1024

    v4i acc[8][4] = {{}};
    v4i av[4], bv[4];

#define RD(off) (*(const v4i*)(lds + (off)))

#define PHASE(slot, ks, mh, STAGES, VMW)                                                   \
    {                                                                                      \
        if ((mh) == 0) {                                                                   \
            bv[0] = RD(bB + (slot) * 32768 + (ks) * 16384 + 0 * 1024);                     \
            bv[1] = RD(bB + (slot) * 32768 + (ks) * 16384 + 1 * 1024);                     \
            bv[2] = RD(bB + (slot) * 32768 + (ks) * 16384 + 2 * 1024);                     \
            bv[3] = RD(bB + (slot) * 32768 + (ks) * 16384 + 3 * 1024);                     \
        }                                                                                  \
        av[0] = RD(aB + (slot) * 32768 + (ks) * 16384 + (mh) * 4096 + 0 * 1024);           \
        av[1] = RD(aB + (slot) * 32768 + (ks) * 16384 + (mh) * 4096 + 1 * 1024);           \
        av[2] = RD(aB + (slot) * 32768 + (ks) * 16384 + (mh) * 4096 + 2 * 1024);           \
        av[3] = RD(aB + (slot) * 32768 + (ks) * 16384 + (mh) * 4096 + 3 * 1024);           \
        STAGES                                                                             \
        __builtin_amdgcn_s_barrier();                                                      \
        asm volatile("s_waitcnt lgkmcnt(0)" ::: "memory");                                 \
        __builtin_amdgcn_s_setprio(1);                                                     \
        _Pragma("unroll")                                                                  \
        for (int mt = 0; mt < 4; ++mt)                                                     \
            _Pragma("unroll")                                                              \
            for (int nt = 0; nt < 4; ++nt)                                                 \
                acc[(mh) * 4 + mt][nt] = __builtin_amdgcn_mfma_i32_16x16x64_i8(            \
                    av[mt], bv[nt], acc[(mh) * 4 + mt][nt], 0, 0, 0);                      \
        __builtin_amdgcn_s_setprio(0);                                                     \
        VMW                                                                                \
        __builtin_amdgcn_s_barrier();                                                      \
    }

#define VM4 asm volatile("s_waitcnt vmcnt(4)" ::: "memory");
#define VM0 asm volatile("s_waitcnt vmcnt(0)" ::: "memory");

    // Prologue: tile0 (both K-halves) + tile1.k0  (12 loads/wave).
    STAGE(0, gA, 0, 0, 0) STAGE(65536, gB, 0, 0, 0)
    STAGE(0, gA, 0, 1, 0) STAGE(65536, gB, 0, 1, 0)
    STAGE(0, gA, 1, 0, 128) STAGE(65536, gB, 1, 0, 128)
    VM4                                  // tile0 fully landed; tile1.k0 may fly
    __builtin_amdgcn_s_barrier();

#pragma unroll 1
    for (int i = 0; i < 15; ++i) {
        const int kb = i * 256;
        PHASE(0, 0, 0, STAGE(0, gA, 1, 1, kb + 128), )
        PHASE(0, 0, 1, STAGE(65536, gB, 1, 1, kb + 128), )
        PHASE(0, 1, 0, STAGE(0, gA, 0, 0, kb + 256), )
        PHASE(0, 1, 1, STAGE(65536, gB, 0, 0, kb + 256), VM4)
        PHASE(1, 0, 0, STAGE(0, gA, 0, 1, kb + 256), )
        PHASE(1, 0, 1, STAGE(65536, gB, 0, 1, kb + 256), )
        PHASE(1, 1, 0, STAGE(0, gA, 1, 0, kb + 384), )
        PHASE(1, 1, 1, STAGE(65536, gB, 1, 0, kb + 384), VM4)
    }
    // Peeled last iteration (tiles 30, 31): only tile31.k1 still to stage.
    PHASE(0, 0, 0, STAGE(0, gA, 1, 1, 3968), )
    PHASE(0, 0, 1, STAGE(65536, gB, 1, 1, 3968), )
    PHASE(0, 1, 0, , )
    PHASE(0, 1, 1, , VM0)
    PHASE(1, 0, 0, , )
    PHASE(1, 0, 1, , )
    PHASE(1, 1, 0, , )
    PHASE(1, 1, 1, , )

    // Epilogue: D layout col = lane&15, row = (lane>>4)*4 + reg.
    const float fs = w_scale[0] * in_scale[0];
    float* Cb = C + (size_t)(bm * 256 + wr * 128 + q * 4) * NDIM + bn * 256 + wc * 64 + lm;
#pragma unroll
    for (int m = 0; m < 8; ++m)
#pragma unroll
        for (int n = 0; n < 4; ++n)
#pragma unroll
            for (int r = 0; r < 4; ++r)
                Cb[(size_t)(m * 16 + r) * NDIM + n * 16] = (float)acc[m][n][r] * fs;

#undef STAGE
#undef RD
#undef PHASE
#undef VM4
#undef VM0
}

extern "C" void kernel_launch(void* const* d_in, const int* in_sizes, int n_in,
                              void* d_out, int out_size, void* d_ws, size_t ws_size,
                              hipStream_t stream) {
    const float* x        = (const float*)d_in[0];
    const int*   w        = (const int*)d_in[1];
    const float* w_scale  = (const float*)d_in[2];
    const float* in_scale = (const float*)d_in[3];
    float* out = (float*)d_out;

    int8_t* xq = (int8_t*)d_ws;                       // 33,554,432 B
    int8_t* wq = xq + (size_t)MDIM * KDIM;            // 16,777,216 B (48 MB total)

    prep_k<<<QBLOCKS + WBLOCKS, 256, 0, stream>>>(
        (const float4*)x, (int4*)xq, (const int4*)w, (int4*)wq, in_scale);

    gemm_i8_k<<<512, 512, 0, stream>>>(xq, wq, out, w_scale, in_scale);
}